// Round 1
// baseline (168.850 us; speedup 1.0000x reference)
//
#include <hip/hip_runtime.h>
#include <hip/hip_bf16.h>

// Problem constants
#define N_IN   65536
#define N_OUTP 16384
#define KNB    16
#define FDIM   64
#define M_DIM  32          // N_DIST * N_PHI
#define KDIM   2048        // M_DIM * FDIM
#define OUT_D  256
#define TN     32          // output rows per block
#define NBLK   (N_OUTP / TN)   // 512

typedef __bf16 bf16x8_t __attribute__((ext_vector_type(8)));
typedef float  f32x4_t  __attribute__((ext_vector_type(4)));

// LDS layout (bytes):
//   [0, 131072)        A fragments: [mt(2)][kk(64)][lane(64)][16B]
//   [131072, 147456)   wbuf: float[8][16][32]
//   [147456, 148480)   winv: float[8][32]
//   [148480, 148992)   idxb: int[8][16]
#define LDS_BYTES 148992
#define WBUF_OFF  131072
#define WINV_OFF  147456
#define IDX_OFF   148480

// Pack W_out (2048x256 f32, row-major) into bf16 B-fragments for
// mfma_f32_16x16x32_bf16: chunk c = (kk, nt, lane); lane l holds
// B[kk*32 + (l>>4)*8 + j][nt*16 + (l&15)], j=0..7.
__global__ __launch_bounds__(256) void pack_B_kernel(
    const float* __restrict__ W, uint4* __restrict__ Bws)
{
  int c    = blockIdx.x * 256 + threadIdx.x;   // 65536 chunks
  int lane = c & 63;
  int nt   = (c >> 6) & 15;
  int kk   = c >> 10;
  int row0 = kk * 32 + (lane >> 4) * 8;
  int col  = nt * 16 + (lane & 15);
  union { unsigned short s[8]; uint4 v; } u;
#pragma unroll
  for (int j = 0; j < 8; ++j) {
    float f = W[(row0 + j) * OUT_D + col];
    __bf16 b = (__bf16)f;
    u.s[j] = __builtin_bit_cast(unsigned short, b);
  }
  Bws[c] = u.v;
}

__global__ __launch_bounds__(256) void fused_kernel(
    const float* __restrict__ x,
    const float* __restrict__ d_dists,
    const float* __restrict__ d_phi,
    const float* __restrict__ dists,
    const float* __restrict__ sigma_p,
    const float* __restrict__ kappa_p,
    const float* __restrict__ phi,
    const uint4* __restrict__ Bws,
    const int*   __restrict__ nh_idx,
    float*       __restrict__ out)
{
  extern __shared__ char smem[];
  float* wbuf = (float*)(smem + WBUF_OFF);   // [8][16][32]
  float* winv = (float*)(smem + WINV_OFF);   // [8][32]
  int*   idxb = (int*)(smem + IDX_OFF);      // [8][16]

  const int t  = threadIdx.x;
  const int n0 = blockIdx.x * TN;

  const float sig  = sigma_p[0];
  const float kap  = kappa_p[0];
  const float sinv = 1.0f / sig;
  float phiv[8], distv[4];
#pragma unroll
  for (int p = 0; p < 8; ++p) phiv[p] = phi[p];
#pragma unroll
  for (int d = 0; d < 4; ++d) distv[d] = dists[d];

  // ---------------- Phase 1: weights + gather + agg -> A frags in LDS ----
  for (int q = 0; q < 4; ++q) {
    const int rbase = q * 8;

    // w compute: thread -> (r8 = (t>>1)>>4, k = (t>>1)&15, rep = t&1)
    {
      int rk = t >> 1, r8 = rk >> 4, k = rk & 15, rep = t & 1;
      int n = n0 + rbase + r8;
      float dd = d_dists[n * KNB + k];
      float dp = d_phi[n * KNB + k];
      float wp[8];
#pragma unroll
      for (int p = 0; p < 8; ++p) wp[p] = __expf(kap * __cosf(dp - phiv[p]));
#pragma unroll
      for (int dl = 0; dl < 2; ++dl) {
        int d = rep * 2 + dl;
        float td = (dd - distv[d]) * sinv;
        float wd = __expf(-0.5f * td * td);
        float4 w0 = make_float4(wd * wp[0], wd * wp[1], wd * wp[2], wd * wp[3]);
        float4 w1 = make_float4(wd * wp[4], wd * wp[5], wd * wp[6], wd * wp[7]);
        float* dst = wbuf + (r8 * 16 + k) * 32 + d * 8;
        *(float4*)(dst)     = w0;
        *(float4*)(dst + 4) = w1;
      }
      if (t < 128) {
        int r8b = t >> 4, kb = t & 15;
        idxb[r8b * 16 + kb] = nh_idx[(n0 + rbase + r8b) * KNB + kb];
      }
    }
    __syncthreads();

    // denominators: thread -> (r8 = t>>5, m = t&31)
    {
      int r8 = t >> 5, m = t & 31;
      float s = 0.f;
#pragma unroll
      for (int k = 0; k < 16; ++k) s += wbuf[(r8 * 16 + k) * 32 + m];
      winv[r8 * 32 + m] = 1.0f / (s + 1e-9f);
    }
    __syncthreads();

    // agg: thread -> (fg = t&31 [f-pair], r8 = t>>5)
    {
      int fg = t & 31, r8 = t >> 5;
      float acc0[32], acc1[32];
#pragma unroll
      for (int m = 0; m < 32; ++m) { acc0[m] = 0.f; acc1[m] = 0.f; }
      const float2* xp = (const float2*)x;
      for (int k = 0; k < 16; ++k) {
        int idx = idxb[r8 * 16 + k];
        float2 xv = xp[idx * 32 + fg];
        const float4* wrow4 = (const float4*)(wbuf + (r8 * 16 + k) * 32);
#pragma unroll
        for (int mm = 0; mm < 8; ++mm) {
          float4 wv = wrow4[mm];
          acc0[mm * 4 + 0] += wv.x * xv.x;  acc1[mm * 4 + 0] += wv.x * xv.y;
          acc0[mm * 4 + 1] += wv.y * xv.x;  acc1[mm * 4 + 1] += wv.y * xv.y;
          acc0[mm * 4 + 2] += wv.z * xv.x;  acc1[mm * 4 + 2] += wv.z * xv.y;
          acc0[mm * 4 + 3] += wv.w * xv.x;  acc1[mm * 4 + 3] += wv.w * xv.y;
        }
      }
      int rg  = rbase + r8;       // row within block, 0..31
      int mt  = rg >> 4;
      int r15 = rg & 15;
#pragma unroll
      for (int m = 0; m < 32; ++m) {
        float wn = winv[r8 * 32 + m];
        float v0 = acc0[m] * wn;
        float v1 = acc1[m] * wn;
        int kg = m * 64 + fg * 2;   // K index in [0,2048)
        // A-fragment stream address
        int byte = mt * 65536 + (kg >> 5) * 1024 + ((kg >> 3) & 3) * 256
                 + r15 * 16 + (kg & 7) * 2;
        __bf16 b0 = (__bf16)v0, b1 = (__bf16)v1;
        unsigned pk = ((unsigned)__builtin_bit_cast(unsigned short, b1) << 16)
                    |  (unsigned)__builtin_bit_cast(unsigned short, b0);
        *(unsigned*)(smem + byte) = pk;
      }
    }
    __syncthreads();
  }

  // ---------------- Phase 2: MFMA GEMM 32x256 = A(32x2048) @ B(2048x256) --
  {
    const int lane = t & 63;
    const int wave = t >> 6;

    f32x4_t cacc[2][4];
#pragma unroll
    for (int mt = 0; mt < 2; ++mt)
#pragma unroll
      for (int i = 0; i < 4; ++i)
        cacc[mt][i] = (f32x4_t){0.f, 0.f, 0.f, 0.f};

    for (int kk = 0; kk < 64; ++kk) {
      bf16x8_t a0 = __builtin_bit_cast(bf16x8_t,
          *(const uint4*)(smem + kk * 1024 + lane * 16));
      bf16x8_t a1 = __builtin_bit_cast(bf16x8_t,
          *(const uint4*)(smem + 65536 + kk * 1024 + lane * 16));
#pragma unroll
      for (int i = 0; i < 4; ++i) {
        uint4 braw = Bws[(kk * 16 + wave * 4 + i) * 64 + lane];
        bf16x8_t b = __builtin_bit_cast(bf16x8_t, braw);
        cacc[0][i] = __builtin_amdgcn_mfma_f32_16x16x32_bf16(a0, b, cacc[0][i], 0, 0, 0);
        cacc[1][i] = __builtin_amdgcn_mfma_f32_16x16x32_bf16(a1, b, cacc[1][i], 0, 0, 0);
      }
    }

    // C/D layout: col = lane&15, row = (lane>>4)*4 + reg  [verified m89]
#pragma unroll
    for (int mt = 0; mt < 2; ++mt)
#pragma unroll
      for (int i = 0; i < 4; ++i)
#pragma unroll
        for (int reg = 0; reg < 4; ++reg) {
          int row = n0 + mt * 16 + (lane >> 4) * 4 + reg;
          int col = wave * 64 + i * 16 + (lane & 15);
          out[row * OUT_D + col] = cacc[mt][i][reg];
        }
  }
}

extern "C" void kernel_launch(void* const* d_in, const int* in_sizes, int n_in,
                              void* d_out, int out_size, void* d_ws, size_t ws_size,
                              hipStream_t stream) {
  const float* x      = (const float*)d_in[0];
  const float* dd     = (const float*)d_in[1];
  const float* dp     = (const float*)d_in[2];
  const float* dists  = (const float*)d_in[3];
  const float* sigma  = (const float*)d_in[4];
  const float* kappa  = (const float*)d_in[5];
  const float* phi    = (const float*)d_in[6];
  const float* W      = (const float*)d_in[7];
  const int*   nh     = (const int*)d_in[8];
  float*       out    = (float*)d_out;
  uint4*       Bws    = (uint4*)d_ws;   // 1 MB: 65536 x 16B B-fragments

  pack_B_kernel<<<256, 256, 0, stream>>>(W, Bws);

  hipFuncSetAttribute((const void*)fused_kernel,
                      hipFuncAttributeMaxDynamicSharedMemorySize, LDS_BYTES);
  fused_kernel<<<NBLK, 256, LDS_BYTES, stream>>>(
      x, dd, dp, dists, sigma, kappa, phi, Bws, nh, out);
}

// Round 2
// 111.606 us; speedup vs baseline: 1.5129x; 1.5129x over previous
//
#include <hip/hip_runtime.h>
#include <hip/hip_bf16.h>

// Problem constants
#define N_IN   65536
#define N_OUTP 16384
#define KNB    16
#define FDIM   64
#define M_DIM  32          // N_DIST * N_PHI
#define KDIM   2048        // M_DIM * FDIM
#define OUT_D  256

typedef __bf16 bf16x8_t __attribute__((ext_vector_type(8)));
typedef float  f32x4_t  __attribute__((ext_vector_type(4)));

// ---------------------------------------------------------------------------
// pack_B: W_out (2048x256 f32, row-major) -> bf16 B-fragments for
// mfma_f32_16x16x32_bf16. Chunk c = (kk, nt, lane); lane l holds
// B[kk*32 + (l>>4)*8 + j][nt*16 + (l&15)], j = 0..7.
// ---------------------------------------------------------------------------
__global__ __launch_bounds__(256) void pack_B_kernel(
    const float* __restrict__ W, uint4* __restrict__ Bws)
{
  int c    = blockIdx.x * 256 + threadIdx.x;   // 65536 chunks
  int lane = c & 63;
  int nt   = (c >> 6) & 15;
  int kk   = c >> 10;
  int row0 = kk * 32 + (lane >> 4) * 8;
  int col  = nt * 16 + (lane & 15);
  union { unsigned short s[8]; uint4 v; } u;
#pragma unroll
  for (int j = 0; j < 8; ++j) {
    float f = W[(row0 + j) * OUT_D + col];
    __bf16 b = (__bf16)f;
    u.s[j] = __builtin_bit_cast(unsigned short, b);
  }
  Bws[c] = u.v;
}

// ---------------------------------------------------------------------------
// agg: weights + gather + normalize -> row-major bf16 A [N_OUTP][KDIM] in ws.
// 8 output rows per block, 2048 blocks. LDS ~17.5 KB -> high occupancy.
// ---------------------------------------------------------------------------
#define AGG_ROWS 8
__global__ __launch_bounds__(256) void agg_kernel(
    const float* __restrict__ x,
    const float* __restrict__ d_dists,
    const float* __restrict__ d_phi,
    const float* __restrict__ dists,
    const float* __restrict__ sigma_p,
    const float* __restrict__ kappa_p,
    const float* __restrict__ phi,
    const int*   __restrict__ nh_idx,
    unsigned*    __restrict__ Aws)     // row-major A, u32 = 2 packed bf16
{
  __shared__ float wbuf[AGG_ROWS * 16 * 32];
  __shared__ float winv[AGG_ROWS * 32];
  __shared__ int   idxb[AGG_ROWS * 16];

  const int t  = threadIdx.x;
  const int n0 = blockIdx.x * AGG_ROWS;

  const float sinv = 1.0f / sigma_p[0];
  const float kap  = kappa_p[0];
  float phiv[8], distv[4];
#pragma unroll
  for (int p = 0; p < 8; ++p) phiv[p] = phi[p];
#pragma unroll
  for (int d = 0; d < 4; ++d) distv[d] = dists[d];

  // weights: thread -> (r8 = (t>>1)>>4, k = (t>>1)&15, rep = t&1)
  {
    int rk = t >> 1, r8 = rk >> 4, k = rk & 15, rep = t & 1;
    int n = n0 + r8;
    float dd = d_dists[n * KNB + k];
    float dp = d_phi[n * KNB + k];
    float wp[8];
#pragma unroll
    for (int p = 0; p < 8; ++p) wp[p] = __expf(kap * __cosf(dp - phiv[p]));
#pragma unroll
    for (int dl = 0; dl < 2; ++dl) {
      int d = rep * 2 + dl;
      float td = (dd - distv[d]) * sinv;
      float wd = __expf(-0.5f * td * td);
      float4 w0 = make_float4(wd * wp[0], wd * wp[1], wd * wp[2], wd * wp[3]);
      float4 w1 = make_float4(wd * wp[4], wd * wp[5], wd * wp[6], wd * wp[7]);
      float* dst = wbuf + (r8 * 16 + k) * 32 + d * 8;
      *(float4*)(dst)     = w0;
      *(float4*)(dst + 4) = w1;
    }
    if (t < 128) {
      int r8b = t >> 4, kb = t & 15;
      idxb[r8b * 16 + kb] = nh_idx[(n0 + r8b) * KNB + kb];
    }
  }
  __syncthreads();

  // denominators: thread -> (r8 = t>>5, m = t&31)
  {
    int r8 = t >> 5, m = t & 31;
    float s = 0.f;
#pragma unroll
    for (int k = 0; k < 16; ++k) s += wbuf[(r8 * 16 + k) * 32 + m];
    winv[r8 * 32 + m] = 1.0f / (s + 1e-9f);
  }
  __syncthreads();

  // agg + store: thread -> (fg = t&31 [f-pair], r8 = t>>5)
  {
    int fg = t & 31, r8 = t >> 5;
    float acc0[32], acc1[32];
#pragma unroll
    for (int m = 0; m < 32; ++m) { acc0[m] = 0.f; acc1[m] = 0.f; }
    const float2* xp = (const float2*)x;
#pragma unroll
    for (int k = 0; k < 16; ++k) {
      int idx = idxb[r8 * 16 + k];
      float2 xv = xp[idx * 32 + fg];
      const float4* wrow4 = (const float4*)(wbuf + (r8 * 16 + k) * 32);
#pragma unroll
      for (int mm = 0; mm < 8; ++mm) {
        float4 wv = wrow4[mm];
        acc0[mm * 4 + 0] += wv.x * xv.x;  acc1[mm * 4 + 0] += wv.x * xv.y;
        acc0[mm * 4 + 1] += wv.y * xv.x;  acc1[mm * 4 + 1] += wv.y * xv.y;
        acc0[mm * 4 + 2] += wv.z * xv.x;  acc1[mm * 4 + 2] += wv.z * xv.y;
        acc0[mm * 4 + 3] += wv.w * xv.x;  acc1[mm * 4 + 3] += wv.w * xv.y;
      }
    }
    int row = n0 + r8;
    unsigned* dst = Aws + row * (KDIM / 2) + fg;  // u32 index = m*32 + fg
#pragma unroll
    for (int m = 0; m < 32; ++m) {
      float wn = winv[r8 * 32 + m];
      __bf16 b0 = (__bf16)(acc0[m] * wn);
      __bf16 b1 = (__bf16)(acc1[m] * wn);
      unsigned pk = ((unsigned)__builtin_bit_cast(unsigned short, b1) << 16)
                  |  (unsigned)__builtin_bit_cast(unsigned short, b0);
      dst[m * 32] = pk;
    }
  }
}

// ---------------------------------------------------------------------------
// gemm: out(16384x256) = A(16384x2048 bf16, row-major in ws) @ B-frags.
// No LDS, no barriers. Block = 32 rows x 128 cols, 1024 blocks x 4 waves.
// A-frag for 16x16x32: lane l reads 16B at row(l&15), k-offset (l>>4)*16B.
// ---------------------------------------------------------------------------
__global__ __launch_bounds__(256) void gemm_kernel(
    const char*  __restrict__ Aws,
    const uint4* __restrict__ Bws,
    float*       __restrict__ out)
{
  const int bx   = blockIdx.x;
  const int rb   = bx >> 1;          // row block: 32 rows
  const int ch   = bx & 1;           // col half: 128 cols
  const int t    = threadIdx.x;
  const int lane = t & 63;
  const int w    = t >> 6;

  f32x4_t cacc[2][2];
#pragma unroll
  for (int mt = 0; mt < 2; ++mt)
#pragma unroll
    for (int i = 0; i < 2; ++i)
      cacc[mt][i] = (f32x4_t){0.f, 0.f, 0.f, 0.f};

  const char* pa0 = Aws + (size_t)(rb * 32 + (lane & 15)) * (KDIM * 2)
                        + (lane >> 4) * 16;
  const char* pa1 = pa0 + 16 * (KDIM * 2);
  const int ntbase = ch * 8 + w * 2;                 // col-tile base
  const uint4* pb  = Bws + ntbase * 64 + lane;

#pragma unroll 4
  for (int kk = 0; kk < 64; ++kk) {
    bf16x8_t a0 = __builtin_bit_cast(bf16x8_t, *(const uint4*)(pa0 + kk * 64));
    bf16x8_t a1 = __builtin_bit_cast(bf16x8_t, *(const uint4*)(pa1 + kk * 64));
    bf16x8_t b0 = __builtin_bit_cast(bf16x8_t, pb[kk * 1024]);
    bf16x8_t b1 = __builtin_bit_cast(bf16x8_t, pb[kk * 1024 + 64]);
    cacc[0][0] = __builtin_amdgcn_mfma_f32_16x16x32_bf16(a0, b0, cacc[0][0], 0, 0, 0);
    cacc[1][0] = __builtin_amdgcn_mfma_f32_16x16x32_bf16(a1, b0, cacc[1][0], 0, 0, 0);
    cacc[0][1] = __builtin_amdgcn_mfma_f32_16x16x32_bf16(a0, b1, cacc[0][1], 0, 0, 0);
    cacc[1][1] = __builtin_amdgcn_mfma_f32_16x16x32_bf16(a1, b1, cacc[1][1], 0, 0, 0);
  }

  // C/D layout: col = lane&15, row = (lane>>4)*4 + reg
#pragma unroll
  for (int mt = 0; mt < 2; ++mt)
#pragma unroll
    for (int i = 0; i < 2; ++i)
#pragma unroll
      for (int reg = 0; reg < 4; ++reg) {
        int row = rb * 32 + mt * 16 + (lane >> 4) * 4 + reg;
        int col = ch * 128 + w * 32 + i * 16 + (lane & 15);
        out[row * OUT_D + col] = cacc[mt][i][reg];
      }
}

// ===========================================================================
// Fallback (R1 fused kernel) — used only if ws_size is too small for A.
// ===========================================================================
#define TN 32
#define NBLK (N_OUTP / TN)
#define LDS_BYTES 148992
#define WBUF_OFF  131072
#define WINV_OFF  147456
#define IDX_OFF   148480

__global__ __launch_bounds__(256) void fused_kernel(
    const float* __restrict__ x,
    const float* __restrict__ d_dists,
    const float* __restrict__ d_phi,
    const float* __restrict__ dists,
    const float* __restrict__ sigma_p,
    const float* __restrict__ kappa_p,
    const float* __restrict__ phi,
    const uint4* __restrict__ Bws,
    const int*   __restrict__ nh_idx,
    float*       __restrict__ out)
{
  extern __shared__ char smem[];
  float* wbuf = (float*)(smem + WBUF_OFF);
  float* winv = (float*)(smem + WINV_OFF);
  int*   idxb = (int*)(smem + IDX_OFF);

  const int t  = threadIdx.x;
  const int n0 = blockIdx.x * TN;

  const float sinv = 1.0f / sigma_p[0];
  const float kap  = kappa_p[0];
  float phiv[8], distv[4];
#pragma unroll
  for (int p = 0; p < 8; ++p) phiv[p] = phi[p];
#pragma unroll
  for (int d = 0; d < 4; ++d) distv[d] = dists[d];

  for (int q = 0; q < 4; ++q) {
    const int rbase = q * 8;
    {
      int rk = t >> 1, r8 = rk >> 4, k = rk & 15, rep = t & 1;
      int n = n0 + rbase + r8;
      float dd = d_dists[n * KNB + k];
      float dp = d_phi[n * KNB + k];
      float wp[8];
#pragma unroll
      for (int p = 0; p < 8; ++p) wp[p] = __expf(kap * __cosf(dp - phiv[p]));
#pragma unroll
      for (int dl = 0; dl < 2; ++dl) {
        int d = rep * 2 + dl;
        float td = (dd - distv[d]) * sinv;
        float wd = __expf(-0.5f * td * td);
        float4 w0 = make_float4(wd * wp[0], wd * wp[1], wd * wp[2], wd * wp[3]);
        float4 w1 = make_float4(wd * wp[4], wd * wp[5], wd * wp[6], wd * wp[7]);
        float* dst = wbuf + (r8 * 16 + k) * 32 + d * 8;
        *(float4*)(dst)     = w0;
        *(float4*)(dst + 4) = w1;
      }
      if (t < 128) {
        int r8b = t >> 4, kb = t & 15;
        idxb[r8b * 16 + kb] = nh_idx[(n0 + rbase + r8b) * KNB + kb];
      }
    }
    __syncthreads();
    {
      int r8 = t >> 5, m = t & 31;
      float s = 0.f;
#pragma unroll
      for (int k = 0; k < 16; ++k) s += wbuf[(r8 * 16 + k) * 32 + m];
      winv[r8 * 32 + m] = 1.0f / (s + 1e-9f);
    }
    __syncthreads();
    {
      int fg = t & 31, r8 = t >> 5;
      float acc0[32], acc1[32];
#pragma unroll
      for (int m = 0; m < 32; ++m) { acc0[m] = 0.f; acc1[m] = 0.f; }
      const float2* xp = (const float2*)x;
      for (int k = 0; k < 16; ++k) {
        int idx = idxb[r8 * 16 + k];
        float2 xv = xp[idx * 32 + fg];
        const float4* wrow4 = (const float4*)(wbuf + (r8 * 16 + k) * 32);
#pragma unroll
        for (int mm = 0; mm < 8; ++mm) {
          float4 wv = wrow4[mm];
          acc0[mm * 4 + 0] += wv.x * xv.x;  acc1[mm * 4 + 0] += wv.x * xv.y;
          acc0[mm * 4 + 1] += wv.y * xv.x;  acc1[mm * 4 + 1] += wv.y * xv.y;
          acc0[mm * 4 + 2] += wv.z * xv.x;  acc1[mm * 4 + 2] += wv.z * xv.y;
          acc0[mm * 4 + 3] += wv.w * xv.x;  acc1[mm * 4 + 3] += wv.w * xv.y;
        }
      }
      int rg  = rbase + r8;
      int mt  = rg >> 4;
      int r15 = rg & 15;
#pragma unroll
      for (int m = 0; m < 32; ++m) {
        float wn = winv[r8 * 32 + m];
        float v0 = acc0[m] * wn;
        float v1 = acc1[m] * wn;
        int kg = m * 64 + fg * 2;
        int byte = mt * 65536 + (kg >> 5) * 1024 + ((kg >> 3) & 3) * 256
                 + r15 * 16 + (kg & 7) * 2;
        __bf16 b0 = (__bf16)v0, b1 = (__bf16)v1;
        unsigned pk = ((unsigned)__builtin_bit_cast(unsigned short, b1) << 16)
                    |  (unsigned)__builtin_bit_cast(unsigned short, b0);
        *(unsigned*)(smem + byte) = pk;
      }
    }
    __syncthreads();
  }

  {
    const int lane = t & 63;
    const int wave = t >> 6;
    f32x4_t cacc[2][4];
#pragma unroll
    for (int mt = 0; mt < 2; ++mt)
#pragma unroll
      for (int i = 0; i < 4; ++i)
        cacc[mt][i] = (f32x4_t){0.f, 0.f, 0.f, 0.f};
    for (int kk = 0; kk < 64; ++kk) {
      bf16x8_t a0 = __builtin_bit_cast(bf16x8_t,
          *(const uint4*)(smem + kk * 1024 + lane * 16));
      bf16x8_t a1 = __builtin_bit_cast(bf16x8_t,
          *(const uint4*)(smem + 65536 + kk * 1024 + lane * 16));
#pragma unroll
      for (int i = 0; i < 4; ++i) {
        uint4 braw = Bws[(kk * 16 + wave * 4 + i) * 64 + lane];
        bf16x8_t b = __builtin_bit_cast(bf16x8_t, braw);
        cacc[0][i] = __builtin_amdgcn_mfma_f32_16x16x32_bf16(a0, b, cacc[0][i], 0, 0, 0);
        cacc[1][i] = __builtin_amdgcn_mfma_f32_16x16x32_bf16(a1, b, cacc[1][i], 0, 0, 0);
      }
    }
#pragma unroll
    for (int mt = 0; mt < 2; ++mt)
#pragma unroll
      for (int i = 0; i < 4; ++i)
#pragma unroll
        for (int reg = 0; reg < 4; ++reg) {
          int row = n0 + mt * 16 + (lane >> 4) * 4 + reg;
          int col = wave * 64 + i * 16 + (lane & 15);
          out[row * OUT_D + col] = cacc[mt][i][reg];
        }
  }
}

// ===========================================================================
extern "C" void kernel_launch(void* const* d_in, const int* in_sizes, int n_in,
                              void* d_out, int out_size, void* d_ws, size_t ws_size,
                              hipStream_t stream) {
  const float* x      = (const float*)d_in[0];
  const float* dd     = (const float*)d_in[1];
  const float* dp     = (const float*)d_in[2];
  const float* dists  = (const float*)d_in[3];
  const float* sigma  = (const float*)d_in[4];
  const float* kappa  = (const float*)d_in[5];
  const float* phi    = (const float*)d_in[6];
  const float* W      = (const float*)d_in[7];
  const int*   nh     = (const int*)d_in[8];
  float*       out    = (float*)d_out;

  uint4* Bws = (uint4*)d_ws;                      // 1 MB of B-fragments
  char*  Aws = (char*)d_ws + (1 << 20);           // 64 MB row-major bf16 A

  const size_t need = (1u << 20) + (size_t)N_OUTP * KDIM * 2;  // 68 MB

  pack_B_kernel<<<256, 256, 0, stream>>>(W, Bws);

  if (ws_size >= need) {
    agg_kernel<<<N_OUTP / AGG_ROWS, 256, 0, stream>>>(
        x, dd, dp, dists, sigma, kappa, phi, nh, (unsigned*)Aws);
    gemm_kernel<<<(N_OUTP / 32) * 2, 256, 0, stream>>>(Aws, Bws, out);
  } else {
    hipFuncSetAttribute((const void*)fused_kernel,
                        hipFuncAttributeMaxDynamicSharedMemorySize, LDS_BYTES);
    fused_kernel<<<NBLK, 256, LDS_BYTES, stream>>>(
        x, dd, dp, dists, sigma, kappa, phi, Bws, nh, out);
  }
}